// Round 1
// baseline (4961.834 us; speedup 1.0000x reference)
//
#include <hip/hip_runtime.h>
#include <hip/hip_bf16.h>

#define NN 8192
#define EE 131072
#define GG 32
#define FF 64
#define DDIM 128
#define NB 8
#define SH 9
#define RMAX 2.03f
#define INV_AVG (1.0f/16.0f)

__device__ __forceinline__ float softplus_f(float v){
  return (v > 20.0f) ? v : log1pf(expf(v));
}

// ---------------- edge geometry: Y, radial basis, envelope ----------------
__global__ __launch_bounds__(256) void k_geom(
    const float* __restrict__ pos, const int* __restrict__ snd, const int* __restrict__ rcv,
    float* __restrict__ Yb, float* __restrict__ Bb, float* __restrict__ Eb)
{
  int e = blockIdx.x*256 + threadIdx.x;
  if (e >= EE) return;
  int s = snd[e], r = rcv[e];
  float dx = pos[3*r  ]-pos[3*s  ];
  float dy = pos[3*r+1]-pos[3*s+1];
  float dz = pos[3*r+2]-pos[3*s+2];
  float d  = sqrtf(dx*dx+dy*dy+dz*dz);
  float dsafe = fmaxf(d, 1e-9f);
  float inv = 1.0f/dsafe;
  float x = dx*inv, y = dy*inv, z = dz*inv;
  const float c1=1.7320508075688772f, c2=3.872983346207417f, c3=1.118033988749895f;
  float Y[SH];
  Y[0]=1.0f; Y[1]=c1*x; Y[2]=c1*y; Y[3]=c1*z;
  Y[4]=c2*x*y; Y[5]=c2*y*z; Y[6]=c3*(3.0f*z*z-1.0f); Y[7]=c2*x*z; Y[8]=0.5f*c2*(x*x-y*y);
  #pragma unroll
  for (int i=0;i<SH;i++) Yb[(size_t)e*SH+i]=Y[i];
  float sc = sqrtf(2.0f/RMAX);
  #pragma unroll
  for (int k=0;k<NB;k++){
    float ang = (float)(k+1)*3.14159265358979f*dsafe/RMAX;
    Bb[(size_t)e*NB+k] = sc*sinf(ang)*inv;
  }
  float tt = fminf(d/RMAX, 1.0f-1e-6f);
  float envv = (d < RMAX) ? expf(-tt*tt/(1.0f-tt*tt)) : 0.0f;
  Eb[e]=envv;
}

// ---------------- x init from embedding table ----------------
__global__ __launch_bounds__(256) void k_init(
    const int* __restrict__ spec, const float* __restrict__ et, float* __restrict__ x)
{
  int i = blockIdx.x*256 + threadIdx.x;   // over NN*FF
  int n = i >> 6, f = i & 63;
  x[i] = et[spec[n]*FF + f];
}

// ---------------- per-edge MLP + message scatter (one wave per edge) ----------------
__global__ __launch_bounds__(256) void k_edge(
  const float* __restrict__ Yb, const float* __restrict__ Bb, const float* __restrict__ Eb,
  const int* __restrict__ snd, const int* __restrict__ rcv,
  const float* __restrict__ x, const float* __restrict__ W1l, const float* __restrict__ W2l,
  float* __restrict__ agg)
{
  __shared__ float sW1[NB*FF];
  __shared__ float sW2[FF*192];
  __shared__ float shh[4][FF];
  int tid = threadIdx.x;
  for (int i=tid;i<NB*FF;i+=256)  sW1[i]=W1l[i];
  for (int i=tid;i<FF*192;i+=256) sW2[i]=W2l[i];
  __syncthreads();
  int lane = tid & 63, wv = tid >> 6;
  int waveId = blockIdx.x*4 + wv;       // 8192 waves, 16 edges each
  for (int it=0; it<16; ++it){
    int e = waveId*16 + it;
    float b[NB];
    #pragma unroll
    for (int k=0;k<NB;k++) b[k]=Bb[(size_t)e*NB+k];
    float hs=0.0f;
    #pragma unroll
    for (int k=0;k<NB;k++) hs += b[k]*sW1[k*FF+lane];
    shh[wv][lane]=softplus_f(hs);
    __syncthreads();
    float o0=0.0f,o1=0.0f,o2=0.0f;
    #pragma unroll 8
    for (int k=0;k<FF;k++){
      float h = shh[wv][k];
      const float* w = &sW2[k*192 + 3*lane];
      o0 += h*w[0]; o1 += h*w[1]; o2 += h*w[2];
    }
    int se = snd[e], re = rcv[e];
    float scale = Eb[e]*INV_AVG*x[se*FF+lane];
    o0*=scale; o1*=scale; o2*=scale;
    float yv[SH];
    #pragma unroll
    for (int sI=0;sI<SH;sI++) yv[sI]=Yb[(size_t)e*SH+sI];
    float* dst = agg + (size_t)re*576 + lane*9;
    unsafeAtomicAdd(dst+0, yv[0]*o0);
    unsafeAtomicAdd(dst+1, yv[1]*o1);
    unsafeAtomicAdd(dst+2, yv[2]*o1);
    unsafeAtomicAdd(dst+3, yv[3]*o1);
    unsafeAtomicAdd(dst+4, yv[4]*o2);
    unsafeAtomicAdd(dst+5, yv[5]*o2);
    unsafeAtomicAdd(dst+6, yv[6]*o2);
    unsafeAtomicAdd(dst+7, yv[7]*o2);
    unsafeAtomicAdd(dst+8, yv[8]*o2);
    __syncthreads();
  }
}

// ---------------- readout: emb[:, colOff:colOff+128] = agg.reshape(N,576) @ Wr ----------------
__global__ __launch_bounds__(128) void k_read(
    const float* __restrict__ agg, const float* __restrict__ Wr,
    float* __restrict__ emb, int colOff)
{
  __shared__ float sa[8*576];
  int t = threadIdx.x;
  size_t n0 = (size_t)blockIdx.x*8;
  const float* src = agg + n0*576;
  for (int i=t;i<8*576;i+=128) sa[i]=src[i];
  __syncthreads();
  float acc[8]={0,0,0,0,0,0,0,0};
  for (int k=0;k<576;k++){
    float w = Wr[k*DDIM + t];
    #pragma unroll
    for (int j=0;j<8;j++) acc[j] += sa[j*576+k]*w;
  }
  #pragma unroll
  for (int j=0;j<8;j++) emb[(n0+j)*256 + colOff + t] = acc[j];
}

// ---------------- node update: x = silu(agg[:,:,0]@W_upd + x@W_self) ----------------
__global__ __launch_bounds__(256) void k_upd(
    const float* __restrict__ agg, const float* __restrict__ xin,
    const float* __restrict__ Wu, const float* __restrict__ Wsf, float* __restrict__ xout)
{
  __shared__ float sWu[FF*FF], sWs[FF*FF];
  __shared__ float sA[4][FF], sX[4][FF];
  int t = threadIdx.x;
  for (int i=t;i<FF*FF;i+=256){ sWu[i]=Wu[i]; sWs[i]=Wsf[i]; }
  int lane = t&63, wv = t>>6;
  int n = blockIdx.x*4 + wv;
  sA[wv][lane] = agg[(size_t)n*576 + lane*9];
  sX[wv][lane] = xin[n*FF + lane];
  __syncthreads();
  float a=0.0f;
  #pragma unroll 8
  for (int k=0;k<FF;k++) a += sA[wv][k]*sWu[k*FF+lane] + sX[wv][k]*sWs[k*FF+lane];
  float sg = 1.0f/(1.0f+expf(-a));
  xout[n*FF+lane] = a*sg;
}

// ---------------- focus logits ----------------
__global__ __launch_bounds__(256) void k_focus(
    const float* __restrict__ emb, const float* __restrict__ wf, float* __restrict__ out)
{
  int lane = threadIdx.x&63, wv = threadIdx.x>>6;
  int n = blockIdx.x*4 + wv;
  float a=0.0f;
  #pragma unroll
  for (int j=0;j<4;j++) a += emb[(size_t)n*256 + j*64 + lane]*wf[j*64+lane];
  #pragma unroll
  for (int off=32; off>0; off>>=1) a += __shfl_down(a, off, 64);
  if (lane==0) out[n]=a;
}

// ---------------- per-graph heads ----------------
__global__ __launch_bounds__(256) void k_head(
    const float* __restrict__ emb, const int* __restrict__ nnode, const int* __restrict__ tspec,
    const float* __restrict__ Ws1, const float* __restrict__ Ws2,
    const float* __restrict__ stab, const float* __restrict__ Wpos,
    float* __restrict__ outSp, float* __restrict__ outPos)
{
  __shared__ float sf[256], sprod[256], sh2[128];
  int g = blockIdx.x, t = threadIdx.x;
  int fi = 0;
  for (int i=0;i<g;i++) fi += nnode[i];
  int ts = tspec[g];
  sf[t] = emb[(size_t)fi*256 + t];
  sprod[t] = sf[t]*stab[ts*256+t];
  __syncthreads();
  if (t < 128){
    float a=0.0f;
    for (int k=0;k<256;k++) a += sf[k]*Ws1[k*128+t];
    sh2[t] = softplus_f(a);
  }
  __syncthreads();
  if (t < 5){
    float a=0.0f;
    for (int k=0;k<128;k++) a += sh2[k]*Ws2[k*5+t];
    outSp[g*5+t]=a;
  }
  for (int p=t;p<1024;p+=256){
    float a=0.0f;
    for (int k=0;k<256;k++) a += sprod[k]*Wpos[k*1024+p];
    outPos[g*1024+p]=a;
  }
}

extern "C" void kernel_launch(void* const* d_in, const int* in_sizes, int n_in,
                              void* d_out, int out_size, void* d_ws, size_t ws_size,
                              hipStream_t stream)
{
  const float* positions = (const float*)d_in[0];
  const int*   species   = (const int*)  d_in[1];
  const int*   senders   = (const int*)  d_in[2];
  const int*   receivers = (const int*)  d_in[3];
  const int*   n_node    = (const int*)  d_in[4];
  const int*   tspec     = (const int*)  d_in[5];
  const float* emb_table = (const float*)d_in[6];
  const float* W1        = (const float*)d_in[7];
  const float* W2        = (const float*)d_in[8];
  const float* W_self    = (const float*)d_in[9];
  const float* W_upd     = (const float*)d_in[10];
  const float* W_read    = (const float*)d_in[11];
  const float* w_focus   = (const float*)d_in[12];
  const float* Ws1       = (const float*)d_in[13];
  const float* Ws2       = (const float*)d_in[14];
  const float* stab      = (const float*)d_in[15];
  const float* W_pos     = (const float*)d_in[16];

  float* ws  = (float*)d_ws;
  float* Yb  = ws;
  float* Bb  = Yb + (size_t)EE*SH;
  float* Eb  = Bb + (size_t)EE*NB;
  float* xA  = Eb + EE;
  float* xB  = xA + (size_t)NN*FF;
  float* agg = xB + (size_t)NN*FF;
  float* emb = agg + (size_t)NN*576;

  float* outFocus = (float*)d_out;
  float* outSp    = outFocus + NN;
  float* outPos   = outSp + GG*5;

  k_geom<<<EE/256,256,0,stream>>>(positions,senders,receivers,Yb,Bb,Eb);
  k_init<<<NN*FF/256,256,0,stream>>>(species,emb_table,xA);

  // ---- layer 0 ----
  hipMemsetAsync(agg, 0, (size_t)NN*576*sizeof(float), stream);
  k_edge<<<EE/64,256,0,stream>>>(Yb,Bb,Eb,senders,receivers,xA,W1,W2,agg);
  k_read<<<NN/8,128,0,stream>>>(agg,W_read,emb,0);
  k_upd<<<NN/4,256,0,stream>>>(agg,xA,W_upd,W_self,xB);

  // ---- layer 1 ----
  hipMemsetAsync(agg, 0, (size_t)NN*576*sizeof(float), stream);
  k_edge<<<EE/64,256,0,stream>>>(Yb,Bb,Eb,senders,receivers,xB,W1+NB*FF,W2+FF*192,agg);
  k_read<<<NN/8,128,0,stream>>>(agg,W_read+576*DDIM,emb,DDIM);

  // ---- heads ----
  k_focus<<<NN/4,256,0,stream>>>(emb,w_focus,outFocus);
  k_head<<<GG,256,0,stream>>>(emb,n_node,tspec,Ws1,Ws2,stab,W_pos,outSp,outPos);
}

// Round 2
// 1102.461 us; speedup vs baseline: 4.5007x; 4.5007x over previous
//
#include <hip/hip_runtime.h>
#include <hip/hip_bf16.h>

#define NN 8192
#define EE 131072
#define GG 32
#define FF 64
#define DDIM 128
#define NB 8
#define SH 9
#define RMAX 2.03f
#define INV_AVG (1.0f/16.0f)

__device__ __forceinline__ float softplus_f(float v){
  return (v > 20.0f) ? v : log1pf(expf(v));
}

// ---------------- edge geometry: Y, radial basis, envelope ----------------
__global__ __launch_bounds__(256) void k_geom(
    const float* __restrict__ pos, const int* __restrict__ snd, const int* __restrict__ rcv,
    float* __restrict__ Yb, float* __restrict__ Bb, float* __restrict__ Eb)
{
  int e = blockIdx.x*256 + threadIdx.x;
  if (e >= EE) return;
  int s = snd[e], r = rcv[e];
  float dx = pos[3*r  ]-pos[3*s  ];
  float dy = pos[3*r+1]-pos[3*s+1];
  float dz = pos[3*r+2]-pos[3*s+2];
  float d  = sqrtf(dx*dx+dy*dy+dz*dz);
  float dsafe = fmaxf(d, 1e-9f);
  float inv = 1.0f/dsafe;
  float x = dx*inv, y = dy*inv, z = dz*inv;
  const float c1=1.7320508075688772f, c2=3.872983346207417f, c3=1.118033988749895f;
  float Y[SH];
  Y[0]=1.0f; Y[1]=c1*x; Y[2]=c1*y; Y[3]=c1*z;
  Y[4]=c2*x*y; Y[5]=c2*y*z; Y[6]=c3*(3.0f*z*z-1.0f); Y[7]=c2*x*z; Y[8]=0.5f*c2*(x*x-y*y);
  #pragma unroll
  for (int i=0;i<SH;i++) Yb[(size_t)e*SH+i]=Y[i];
  float sc = sqrtf(2.0f/RMAX);
  #pragma unroll
  for (int k=0;k<NB;k++){
    float ang = (float)(k+1)*3.14159265358979f*dsafe/RMAX;
    Bb[(size_t)e*NB+k] = sc*sinf(ang)*inv;
  }
  float tt = fminf(d/RMAX, 1.0f-1e-6f);
  float envv = (d < RMAX) ? expf(-tt*tt/(1.0f-tt*tt)) : 0.0f;
  Eb[e]=envv;
}

// ---------------- x init from embedding table ----------------
__global__ __launch_bounds__(256) void k_init(
    const int* __restrict__ spec, const float* __restrict__ et, float* __restrict__ x)
{
  int i = blockIdx.x*256 + threadIdx.x;   // over NN*FF
  int n = i >> 6, f = i & 63;
  x[i] = et[spec[n]*FF + f];
}

// ---------------- CSR build ----------------
__global__ __launch_bounds__(256) void k_deg(const int* __restrict__ rcv, int* __restrict__ deg)
{
  int e = blockIdx.x*256 + threadIdx.x;
  if (e < EE) atomicAdd(&deg[rcv[e]], 1);
}

// single block, 256 threads; each thread owns 32 consecutive nodes
__global__ __launch_bounds__(256) void k_scan(const int* __restrict__ deg,
                                              int* __restrict__ off, int* __restrict__ cur)
{
  __shared__ int part[256];
  int t = threadIdx.x;
  int base = t*32;
  int s = 0;
  for (int i=0;i<32;i++) s += deg[base+i];
  part[t] = s;
  __syncthreads();
  for (int o2=1;o2<256;o2<<=1){
    int v = (t>=o2)? part[t-o2] : 0;
    __syncthreads();
    part[t] += v;
    __syncthreads();
  }
  int run = part[t]-s;   // exclusive prefix of this chunk
  for (int i=0;i<32;i++){
    off[base+i]=run; cur[base+i]=run;
    run += deg[base+i];
  }
  if (t==255) off[NN]=run;
}

__global__ __launch_bounds__(256) void k_fill(const int* __restrict__ rcv,
                                              int* __restrict__ cur, int* __restrict__ eidx)
{
  int e = blockIdx.x*256 + threadIdx.x;
  if (e < EE){
    int p = atomicAdd(&cur[rcv[e]], 1);
    eidx[p] = e;
  }
}

// ---------------- fused edge-MLP + gather aggregate: one wave per node ----------------
__global__ __launch_bounds__(256) void k_gather(
  const float* __restrict__ Yb, const float* __restrict__ Bb, const float* __restrict__ Eb,
  const int* __restrict__ snd,
  const int* __restrict__ off, const int* __restrict__ eidx,
  const float* __restrict__ x, const float* __restrict__ W1l, const float* __restrict__ W2l,
  float* __restrict__ agg)
{
  __shared__ float sW1[NB*FF];     // 2 KB
  __shared__ float sW2[FF*192];    // 48 KB
  int tid = threadIdx.x;
  for (int i=tid;i<NB*FF;i+=256)  sW1[i]=W1l[i];
  for (int i=tid;i<FF*192;i+=256) sW2[i]=W2l[i];
  __syncthreads();
  int lane = tid & 63, wv = tid >> 6;
  int n = blockIdx.x*4 + wv;                 // wave-uniform node
  int js = off[n], je = off[n+1];
  float acc[SH];
  #pragma unroll
  for (int i=0;i<SH;i++) acc[i]=0.0f;

  for (int j0=js; j0<je; j0+=4){
    int m = je - j0; if (m>4) m=4;           // wave-uniform
    int e[4]; float hv[4];
    #pragma unroll
    for (int c=0;c<4;c++){
      hv[c]=0.0f; e[c]=0;
      if (c<m){
        e[c]=eidx[j0+c];
        float hs=0.0f;
        #pragma unroll
        for (int k=0;k<NB;k++) hs += Bb[(size_t)e[c]*NB+k]*sW1[k*FF+lane];
        hv[c]=softplus_f(hs);
      }
    }
    float o[4][3];
    #pragma unroll
    for (int c=0;c<4;c++){ o[c][0]=0.0f; o[c][1]=0.0f; o[c][2]=0.0f; }
    #pragma unroll
    for (int k=0;k<FF;k++){
      float w0=sW2[k*192+3*lane+0];
      float w1=sW2[k*192+3*lane+1];
      float w2=sW2[k*192+3*lane+2];
      #pragma unroll
      for (int c=0;c<4;c++){
        float hk = __uint_as_float(__builtin_amdgcn_readlane(__float_as_uint(hv[c]), k));
        o[c][0] += hk*w0; o[c][1] += hk*w1; o[c][2] += hk*w2;
      }
    }
    #pragma unroll
    for (int c=0;c<4;c++){
      if (c<m){
        int ee=e[c];
        float scale = Eb[ee]*INV_AVG*x[snd[ee]*FF+lane];
        float p0=o[c][0]*scale, p1=o[c][1]*scale, p2=o[c][2]*scale;
        const float* y = &Yb[(size_t)ee*SH];
        acc[0]+=y[0]*p0;
        acc[1]+=y[1]*p1; acc[2]+=y[2]*p1; acc[3]+=y[3]*p1;
        acc[4]+=y[4]*p2; acc[5]+=y[5]*p2; acc[6]+=y[6]*p2;
        acc[7]+=y[7]*p2; acc[8]+=y[8]*p2;
      }
    }
  }
  float* dst = agg + (size_t)n*576 + lane*9;
  #pragma unroll
  for (int i=0;i<SH;i++) dst[i]=acc[i];
}

// ---------------- readout: emb[:, colOff:colOff+128] = agg.reshape(N,576) @ Wr ----------------
__global__ __launch_bounds__(128) void k_read(
    const float* __restrict__ agg, const float* __restrict__ Wr,
    float* __restrict__ emb, int colOff)
{
  __shared__ float sa[8*576];
  int t = threadIdx.x;
  size_t n0 = (size_t)blockIdx.x*8;
  const float* src = agg + n0*576;
  for (int i=t;i<8*576;i+=128) sa[i]=src[i];
  __syncthreads();
  float acc[8]={0,0,0,0,0,0,0,0};
  for (int k=0;k<576;k++){
    float w = Wr[k*DDIM + t];
    #pragma unroll
    for (int j=0;j<8;j++) acc[j] += sa[j*576+k]*w;
  }
  #pragma unroll
  for (int j=0;j<8;j++) emb[(n0+j)*256 + colOff + t] = acc[j];
}

// ---------------- node update: x = silu(agg[:,:,0]@W_upd + x@W_self) ----------------
__global__ __launch_bounds__(256) void k_upd(
    const float* __restrict__ agg, const float* __restrict__ xin,
    const float* __restrict__ Wu, const float* __restrict__ Wsf, float* __restrict__ xout)
{
  __shared__ float sWu[FF*FF], sWs[FF*FF];
  __shared__ float sA[4][FF], sX[4][FF];
  int t = threadIdx.x;
  for (int i=t;i<FF*FF;i+=256){ sWu[i]=Wu[i]; sWs[i]=Wsf[i]; }
  int lane = t&63, wv = t>>6;
  int n = blockIdx.x*4 + wv;
  sA[wv][lane] = agg[(size_t)n*576 + lane*9];
  sX[wv][lane] = xin[n*FF + lane];
  __syncthreads();
  float a=0.0f;
  #pragma unroll 8
  for (int k=0;k<FF;k++) a += sA[wv][k]*sWu[k*FF+lane] + sX[wv][k]*sWs[k*FF+lane];
  float sg = 1.0f/(1.0f+expf(-a));
  xout[n*FF+lane] = a*sg;
}

// ---------------- focus logits ----------------
__global__ __launch_bounds__(256) void k_focus(
    const float* __restrict__ emb, const float* __restrict__ wf, float* __restrict__ out)
{
  int lane = threadIdx.x&63, wv = threadIdx.x>>6;
  int n = blockIdx.x*4 + wv;
  float a=0.0f;
  #pragma unroll
  for (int j=0;j<4;j++) a += emb[(size_t)n*256 + j*64 + lane]*wf[j*64+lane];
  #pragma unroll
  for (int off=32; off>0; off>>=1) a += __shfl_down(a, off, 64);
  if (lane==0) out[n]=a;
}

// ---------------- per-graph heads ----------------
__global__ __launch_bounds__(256) void k_head(
    const float* __restrict__ emb, const int* __restrict__ nnode, const int* __restrict__ tspec,
    const float* __restrict__ Ws1, const float* __restrict__ Ws2,
    const float* __restrict__ stab, const float* __restrict__ Wpos,
    float* __restrict__ outSp, float* __restrict__ outPos)
{
  __shared__ float sf[256], sprod[256], sh2[128];
  int g = blockIdx.x, t = threadIdx.x;
  int fi = 0;
  for (int i=0;i<g;i++) fi += nnode[i];
  int ts = tspec[g];
  sf[t] = emb[(size_t)fi*256 + t];
  sprod[t] = sf[t]*stab[ts*256+t];
  __syncthreads();
  if (t < 128){
    float a=0.0f;
    for (int k=0;k<256;k++) a += sf[k]*Ws1[k*128+t];
    sh2[t] = softplus_f(a);
  }
  __syncthreads();
  if (t < 5){
    float a=0.0f;
    for (int k=0;k<128;k++) a += sh2[k]*Ws2[k*5+t];
    outSp[g*5+t]=a;
  }
  for (int p=t;p<1024;p+=256){
    float a=0.0f;
    for (int k=0;k<256;k++) a += sprod[k]*Wpos[k*1024+p];
    outPos[g*1024+p]=a;
  }
}

extern "C" void kernel_launch(void* const* d_in, const int* in_sizes, int n_in,
                              void* d_out, int out_size, void* d_ws, size_t ws_size,
                              hipStream_t stream)
{
  const float* positions = (const float*)d_in[0];
  const int*   species   = (const int*)  d_in[1];
  const int*   senders   = (const int*)  d_in[2];
  const int*   receivers = (const int*)  d_in[3];
  const int*   n_node    = (const int*)  d_in[4];
  const int*   tspec     = (const int*)  d_in[5];
  const float* emb_table = (const float*)d_in[6];
  const float* W1        = (const float*)d_in[7];
  const float* W2        = (const float*)d_in[8];
  const float* W_self    = (const float*)d_in[9];
  const float* W_upd     = (const float*)d_in[10];
  const float* W_read    = (const float*)d_in[11];
  const float* w_focus   = (const float*)d_in[12];
  const float* Ws1       = (const float*)d_in[13];
  const float* Ws2       = (const float*)d_in[14];
  const float* stab      = (const float*)d_in[15];
  const float* W_pos     = (const float*)d_in[16];

  float* ws  = (float*)d_ws;
  float* Yb  = ws;
  float* Bb  = Yb + (size_t)EE*SH;
  float* Eb  = Bb + (size_t)EE*NB;
  float* xA  = Eb + EE;
  float* xB  = xA + (size_t)NN*FF;
  float* agg = xB + (size_t)NN*FF;
  float* emb = agg + (size_t)NN*576;
  int*   deg = (int*)(emb + (size_t)NN*256);
  int*   off = deg + NN;
  int*   cur = off + (NN+1);
  int*   eidx= cur + NN;

  float* outFocus = (float*)d_out;
  float* outSp    = outFocus + NN;
  float* outPos   = outSp + GG*5;

  // geometry + embeddings + CSR (receiver-sorted edge lists)
  k_geom<<<EE/256,256,0,stream>>>(positions,senders,receivers,Yb,Bb,Eb);
  k_init<<<NN*FF/256,256,0,stream>>>(species,emb_table,xA);
  hipMemsetAsync(deg, 0, NN*sizeof(int), stream);
  k_deg<<<EE/256,256,0,stream>>>(receivers,deg);
  k_scan<<<1,256,0,stream>>>(deg,off,cur);
  k_fill<<<EE/256,256,0,stream>>>(receivers,cur,eidx);

  // ---- layer 0 ----
  k_gather<<<NN/4,256,0,stream>>>(Yb,Bb,Eb,senders,off,eidx,xA,W1,W2,agg);
  k_read<<<NN/8,128,0,stream>>>(agg,W_read,emb,0);
  k_upd<<<NN/4,256,0,stream>>>(agg,xA,W_upd,W_self,xB);

  // ---- layer 1 ----
  k_gather<<<NN/4,256,0,stream>>>(Yb,Bb,Eb,senders,off,eidx,xB,W1+NB*FF,W2+FF*192,agg);
  k_read<<<NN/8,128,0,stream>>>(agg,W_read+576*DDIM,emb,DDIM);

  // ---- heads ----
  k_focus<<<NN/4,256,0,stream>>>(emb,w_focus,outFocus);
  k_head<<<GG,256,0,stream>>>(emb,n_node,tspec,Ws1,Ws2,stab,W_pos,outSp,outPos);
}

// Round 5
// 418.543 us; speedup vs baseline: 11.8550x; 2.6340x over previous
//
#include <hip/hip_runtime.h>
#include <hip/hip_bf16.h>

#define NN 8192
#define EE 131072
#define GG 32
#define FF 64
#define DDIM 128
#define NB 8
#define SH 9
#define RMAX 2.03f
#define INV_AVG (1.0f/16.0f)

typedef __attribute__((ext_vector_type(8))) short short8v;
typedef __attribute__((ext_vector_type(4))) float float4v;

__device__ __forceinline__ float softplus_f(float v){
  return (v > 20.0f) ? v : log1pf(expf(v));
}
__device__ __forceinline__ unsigned short f2bf(float f){
  unsigned int u = __float_as_uint(f);
  unsigned int r = (u + 0x7fffu + ((u>>16)&1u)) >> 16;
  return (unsigned short)r;
}
__device__ __forceinline__ float bf2f(unsigned short h){
  return __uint_as_float(((unsigned int)h)<<16);
}

// ---------------- edge geometry: Y, radial basis, envelope ----------------
__global__ __launch_bounds__(256) void k_geom(
    const float* __restrict__ pos, const int* __restrict__ snd, const int* __restrict__ rcv,
    float* __restrict__ Yb, float* __restrict__ Bb, float* __restrict__ Eb)
{
  int e = blockIdx.x*256 + threadIdx.x;
  if (e >= EE) return;
  int s = snd[e], r = rcv[e];
  float dx = pos[3*r  ]-pos[3*s  ];
  float dy = pos[3*r+1]-pos[3*s+1];
  float dz = pos[3*r+2]-pos[3*s+2];
  float d  = sqrtf(dx*dx+dy*dy+dz*dz);
  float dsafe = fmaxf(d, 1e-9f);
  float inv = 1.0f/dsafe;
  float x = dx*inv, y = dy*inv, z = dz*inv;
  const float c1=1.7320508075688772f, c2=3.872983346207417f, c3=1.118033988749895f;
  float Y[SH];
  Y[0]=1.0f; Y[1]=c1*x; Y[2]=c1*y; Y[3]=c1*z;
  Y[4]=c2*x*y; Y[5]=c2*y*z; Y[6]=c3*(3.0f*z*z-1.0f); Y[7]=c2*x*z; Y[8]=0.5f*c2*(x*x-y*y);
  #pragma unroll
  for (int i=0;i<SH;i++) Yb[(size_t)e*SH+i]=Y[i];
  float sc = sqrtf(2.0f/RMAX);
  #pragma unroll
  for (int k=0;k<NB;k++){
    float ang = (float)(k+1)*3.14159265358979f*dsafe/RMAX;
    Bb[(size_t)e*NB+k] = sc*sinf(ang)*inv;
  }
  float tt = fminf(d/RMAX, 1.0f-1e-6f);
  float envv = (d < RMAX) ? expf(-tt*tt/(1.0f-tt*tt)) : 0.0f;
  Eb[e]=envv;
}

// ---------------- x init from embedding table ----------------
__global__ __launch_bounds__(256) void k_init(
    const int* __restrict__ spec, const float* __restrict__ et, float* __restrict__ x)
{
  int i = blockIdx.x*256 + threadIdx.x;
  int n = i >> 6, f = i & 63;
  x[i] = et[spec[n]*FF + f];
}

// ---------------- CSR build ----------------
__global__ __launch_bounds__(256) void k_deg(const int* __restrict__ rcv, int* __restrict__ deg)
{
  int e = blockIdx.x*256 + threadIdx.x;
  if (e < EE) atomicAdd(&deg[rcv[e]], 1);
}

__global__ __launch_bounds__(256) void k_scan(const int* __restrict__ deg,
                                              int* __restrict__ off, int* __restrict__ cur)
{
  __shared__ int part[256];
  int t = threadIdx.x;
  int base = t*32;
  int s = 0;
  for (int i=0;i<32;i++) s += deg[base+i];
  part[t] = s;
  __syncthreads();
  for (int o2=1;o2<256;o2<<=1){
    int v = (t>=o2)? part[t-o2] : 0;
    __syncthreads();
    part[t] += v;
    __syncthreads();
  }
  int run = part[t]-s;
  for (int i=0;i<32;i++){
    off[base+i]=run; cur[base+i]=run;
    run += deg[base+i];
  }
  if (t==255) off[NN]=run;
}

__global__ __launch_bounds__(256) void k_fill(const int* __restrict__ rcv,
                                              int* __restrict__ cur, int* __restrict__ eidx)
{
  int e = blockIdx.x*256 + threadIdx.x;
  if (e < EE){
    int p = atomicAdd(&cur[rcv[e]], 1);
    eidx[p] = e;
  }
}

// ---------------- H = softplus(B @ W1) in bf16, one layer ----------------
__global__ __launch_bounds__(256) void k_h(
    const float* __restrict__ Bb, const float* __restrict__ W1l,
    unsigned short* __restrict__ H)
{
  int i = blockIdx.x*256 + threadIdx.x;   // over EE*FF
  int e = i >> 6, f = i & 63;
  const float* Brow = Bb + (size_t)e*NB;
  float h = 0.0f;
  #pragma unroll
  for (int k=0;k<NB;k++) h += Brow[k]*W1l[k*FF + f];
  H[i] = f2bf(softplus_f(h));
}

// ---------------- pack W2 (both layers) into MFMA B-frag layout, permuted cols ----------------
// permuted col' = c*64 + f  <->  original col = 3*f + c
// Bp element order: [((li*12+t)*2+s)*64 + lane]*8 + j ; value = W2[li][k][3f+c],
// k = s*32 + (lane>>4)*8 + j, col' = t*16 + (lane&15)
__global__ __launch_bounds__(256) void k_w2pack(
    const float* __restrict__ W2, unsigned short* __restrict__ Bp)
{
  int id = blockIdx.x*256 + threadIdx.x;      // 24576 total
  int j  = id & 7;
  int l  = (id>>3) & 63;
  int s  = (id>>9) & 1;
  int rem = id >> 10;                         // li*12 + t
  int t  = rem % 12;
  int li = rem / 12;
  int k  = s*32 + (l>>4)*8 + j;
  int colp = t*16 + (l&15);
  int f = colp & 63, c = colp >> 6;
  float v = W2[(size_t)li*FF*192 + k*192 + 3*f + c];
  Bp[id] = f2bf(v);
}

// ---------------- O = H @ W2  (bf16 MFMA), O stored bf16 with permuted cols ----------------
__global__ __launch_bounds__(256) void k_gemm2(
    const unsigned short* __restrict__ H, const unsigned short* __restrict__ Bpl,
    unsigned short* __restrict__ O)
{
  int tid = threadIdx.x;
  int lane = tid & 63, wv = tid >> 6;
  int r0 = (blockIdx.x*4 + wv) * 16;
  int mrow = lane & 15, kgrp = lane >> 4;
  const short8v* Arow = (const short8v*)(H + ((size_t)(r0 + mrow))*FF + kgrp*8);
  short8v a0 = Arow[0];      // k = kgrp*8 .. +7
  short8v a1 = Arow[4];      // k + 32
  #pragma unroll
  for (int t=0;t<12;t++){
    short8v b0 = *(const short8v*)(Bpl + ((size_t)(t*2+0)*64 + lane)*8);
    short8v b1 = *(const short8v*)(Bpl + ((size_t)(t*2+1)*64 + lane)*8);
    float4v acc = {0.0f,0.0f,0.0f,0.0f};
    acc = __builtin_amdgcn_mfma_f32_16x16x32_bf16(a0, b0, acc, 0, 0, 0);
    acc = __builtin_amdgcn_mfma_f32_16x16x32_bf16(a1, b1, acc, 0, 0, 0);
    #pragma unroll
    for (int i=0;i<4;i++){
      int row = r0 + kgrp*4 + i;
      O[(size_t)row*192 + t*16 + mrow] = f2bf(acc[i]);
    }
  }
}

// ---------------- gather: per-node wave, read O rows + scale, no LDS ----------------
__global__ __launch_bounds__(256) void k_gather(
  const float* __restrict__ Yb, const float* __restrict__ Eb,
  const int* __restrict__ snd, const int* __restrict__ off, const int* __restrict__ eidx,
  const float* __restrict__ x, const unsigned short* __restrict__ O,
  float* __restrict__ agg)
{
  int lane = threadIdx.x & 63, wv = threadIdx.x >> 6;
  int n = blockIdx.x*4 + wv;
  int js = off[n], je = off[n+1];
  float acc[SH];
  #pragma unroll
  for (int i=0;i<SH;i++) acc[i]=0.0f;
  for (int j=js;j<je;j++){
    int e = eidx[j];
    const unsigned short* orow = O + (size_t)e*192;
    float o0 = bf2f(orow[lane]);
    float o1 = bf2f(orow[64+lane]);
    float o2 = bf2f(orow[128+lane]);
    float scale = Eb[e]*INV_AVG*x[snd[e]*FF+lane];
    const float* y = Yb + (size_t)e*SH;
    float p0=o0*scale, p1=o1*scale, p2=o2*scale;
    acc[0]+=y[0]*p0;
    acc[1]+=y[1]*p1; acc[2]+=y[2]*p1; acc[3]+=y[3]*p1;
    acc[4]+=y[4]*p2; acc[5]+=y[5]*p2; acc[6]+=y[6]*p2;
    acc[7]+=y[7]*p2; acc[8]+=y[8]*p2;
  }
  float* dst = agg + (size_t)n*576 + lane*SH;
  #pragma unroll
  for (int i=0;i<SH;i++) dst[i]=acc[i];
}

// ---------------- readout: emb[:, colOff:+128] = agg.reshape(N,576) @ Wr ----------------
__global__ __launch_bounds__(128) void k_read(
    const float* __restrict__ agg, const float* __restrict__ Wr,
    float* __restrict__ emb, int colOff)
{
  __shared__ float sa[8*576];
  int t = threadIdx.x;
  size_t n0 = (size_t)blockIdx.x*8;
  const float* src = agg + n0*576;
  for (int i=t;i<8*576;i+=128) sa[i]=src[i];
  __syncthreads();
  float acc[8]={0,0,0,0,0,0,0,0};
  for (int k=0;k<576;k++){
    float w = Wr[k*DDIM + t];
    #pragma unroll
    for (int j=0;j<8;j++) acc[j] += sa[j*576+k]*w;
  }
  #pragma unroll
  for (int j=0;j<8;j++) emb[(n0+j)*256 + colOff + t] = acc[j];
}

// ---------------- node update: x = silu(agg[:,:,0]@W_upd + x@W_self) ----------------
__global__ __launch_bounds__(256) void k_upd(
    const float* __restrict__ agg, const float* __restrict__ xin,
    const float* __restrict__ Wu, const float* __restrict__ Wsf, float* __restrict__ xout)
{
  __shared__ float sWu[FF*FF], sWs[FF*FF];
  __shared__ float sA[4][FF], sX[4][FF];
  int t = threadIdx.x;
  for (int i=t;i<FF*FF;i+=256){ sWu[i]=Wu[i]; sWs[i]=Wsf[i]; }
  int lane = t&63, wv = t>>6;
  int n = blockIdx.x*4 + wv;
  sA[wv][lane] = agg[(size_t)n*576 + lane*SH];
  sX[wv][lane] = xin[n*FF + lane];
  __syncthreads();
  float a=0.0f;
  #pragma unroll 8
  for (int k=0;k<FF;k++) a += sA[wv][k]*sWu[k*FF+lane] + sX[wv][k]*sWs[k*FF+lane];
  float sg = 1.0f/(1.0f+expf(-a));
  xout[n*FF+lane] = a*sg;
}

// ---------------- focus logits ----------------
__global__ __launch_bounds__(256) void k_focus(
    const float* __restrict__ emb, const float* __restrict__ wf, float* __restrict__ out)
{
  int lane = threadIdx.x&63, wv = threadIdx.x>>6;
  int n = blockIdx.x*4 + wv;
  float a=0.0f;
  #pragma unroll
  for (int j=0;j<4;j++) a += emb[(size_t)n*256 + j*64 + lane]*wf[j*64+lane];
  #pragma unroll
  for (int off=32; off>0; off>>=1) a += __shfl_down(a, off, 64);
  if (lane==0) out[n]=a;
}

// ---------------- per-graph heads ----------------
__global__ __launch_bounds__(256) void k_head(
    const float* __restrict__ emb, const int* __restrict__ nnode, const int* __restrict__ tspec,
    const float* __restrict__ Ws1, const float* __restrict__ Ws2,
    const float* __restrict__ stab, const float* __restrict__ Wpos,
    float* __restrict__ outSp, float* __restrict__ outPos)
{
  __shared__ float sf[256], sprod[256], sh2[128];
  int g = blockIdx.x, t = threadIdx.x;
  int fi = 0;
  for (int i=0;i<g;i++) fi += nnode[i];
  int ts = tspec[g];
  sf[t] = emb[(size_t)fi*256 + t];
  sprod[t] = sf[t]*stab[ts*256+t];
  __syncthreads();
  if (t < 128){
    float a=0.0f;
    for (int k=0;k<256;k++) a += sf[k]*Ws1[k*128+t];
    sh2[t] = softplus_f(a);
  }
  __syncthreads();
  if (t < 5){
    float a=0.0f;
    for (int k=0;k<128;k++) a += sh2[k]*Ws2[k*5+t];
    outSp[g*5+t]=a;
  }
  for (int p=t;p<1024;p+=256){
    float a=0.0f;
    for (int k=0;k<256;k++) a += sprod[k]*Wpos[k*1024+p];
    outPos[g*1024+p]=a;
  }
}

extern "C" void kernel_launch(void* const* d_in, const int* in_sizes, int n_in,
                              void* d_out, int out_size, void* d_ws, size_t ws_size,
                              hipStream_t stream)
{
  const float* positions = (const float*)d_in[0];
  const int*   species   = (const int*)  d_in[1];
  const int*   senders   = (const int*)  d_in[2];
  const int*   receivers = (const int*)  d_in[3];
  const int*   n_node    = (const int*)  d_in[4];
  const int*   tspec     = (const int*)  d_in[5];
  const float* emb_table = (const float*)d_in[6];
  const float* W1        = (const float*)d_in[7];
  const float* W2        = (const float*)d_in[8];
  const float* W_self    = (const float*)d_in[9];
  const float* W_upd     = (const float*)d_in[10];
  const float* W_read    = (const float*)d_in[11];
  const float* w_focus   = (const float*)d_in[12];
  const float* Ws1       = (const float*)d_in[13];
  const float* Ws2       = (const float*)d_in[14];
  const float* stab      = (const float*)d_in[15];
  const float* W_pos     = (const float*)d_in[16];

  char* base = (char*)d_ws;
  size_t ofs = 0;
  auto alloc = [&](size_t bytes)->char*{
    char* p = base + ofs;
    ofs = (ofs + bytes + 255) & ~(size_t)255;
    return p;
  };
  float* Yb  = (float*)alloc((size_t)EE*SH*4);
  float* Bb  = (float*)alloc((size_t)EE*NB*4);
  float* Eb  = (float*)alloc((size_t)EE*4);
  float* xA  = (float*)alloc((size_t)NN*FF*4);
  float* xB  = (float*)alloc((size_t)NN*FF*4);
  float* agg = (float*)alloc((size_t)NN*576*4);
  float* emb = (float*)alloc((size_t)NN*256*4);
  int*   deg = (int*)  alloc((size_t)NN*4);
  int*   off = (int*)  alloc((size_t)(NN+1)*4);
  int*   cur = (int*)  alloc((size_t)NN*4);
  int*   eidx= (int*)  alloc((size_t)EE*4);
  unsigned short* H  = (unsigned short*)alloc((size_t)EE*FF*2);
  unsigned short* O  = (unsigned short*)alloc((size_t)EE*192*2);
  unsigned short* Bp = (unsigned short*)alloc((size_t)2*12*2*64*8*2);

  float* outFocus = (float*)d_out;
  float* outSp    = outFocus + NN;
  float* outPos   = outSp + GG*5;

  // geometry + embeddings + CSR
  k_geom<<<EE/256,256,0,stream>>>(positions,senders,receivers,Yb,Bb,Eb);
  k_init<<<NN*FF/256,256,0,stream>>>(species,emb_table,xA);
  hipMemsetAsync(deg, 0, NN*sizeof(int), stream);
  k_deg<<<EE/256,256,0,stream>>>(receivers,deg);
  k_scan<<<1,256,0,stream>>>(deg,off,cur);
  k_fill<<<EE/256,256,0,stream>>>(receivers,cur,eidx);
  k_w2pack<<<96,256,0,stream>>>(W2,Bp);

  // ---- layer 0 ----
  k_h<<<EE*FF/256,256,0,stream>>>(Bb,W1,H);
  k_gemm2<<<EE/64,256,0,stream>>>(H,Bp,O);
  k_gather<<<NN/4,256,0,stream>>>(Yb,Eb,senders,off,eidx,xA,O,agg);
  k_read<<<NN/8,128,0,stream>>>(agg,W_read,emb,0);
  k_upd<<<NN/4,256,0,stream>>>(agg,xA,W_upd,W_self,xB);

  // ---- layer 1 ----
  k_h<<<EE*FF/256,256,0,stream>>>(Bb,W1+NB*FF,H);
  k_gemm2<<<EE/64,256,0,stream>>>(H,Bp+(size_t)12*2*64*8,O);
  k_gather<<<NN/4,256,0,stream>>>(Yb,Eb,senders,off,eidx,xB,O,agg);
  k_read<<<NN/8,128,0,stream>>>(agg,W_read+576*DDIM,emb,DDIM);

  // ---- heads ----
  k_focus<<<NN/4,256,0,stream>>>(emb,w_focus,outFocus);
  k_head<<<GG,256,0,stream>>>(emb,n_node,tspec,Ws1,Ws2,stab,W_pos,outSp,outPos);
}

// Round 6
// 381.717 us; speedup vs baseline: 12.9987x; 1.0965x over previous
//
#include <hip/hip_runtime.h>
#include <hip/hip_bf16.h>

#define NN 8192
#define EE 131072
#define GG 32
#define FF 64
#define DDIM 128
#define NB 8
#define SH 9
#define RMAX 2.03f
#define INV_AVG (1.0f/16.0f)

typedef __attribute__((ext_vector_type(8))) short short8v;
typedef __attribute__((ext_vector_type(4))) float float4v;

__device__ __forceinline__ float softplus_f(float v){
  return (v > 20.0f) ? v : log1pf(expf(v));
}
__device__ __forceinline__ unsigned short f2bf(float f){
  unsigned int u = __float_as_uint(f);
  unsigned int r = (u + 0x7fffu + ((u>>16)&1u)) >> 16;
  return (unsigned short)r;
}
__device__ __forceinline__ float bf2f(unsigned short h){
  return __uint_as_float(((unsigned int)h)<<16);
}

// ---------------- edge geometry: Y, radial basis (sin recurrence), envelope ----------------
__global__ __launch_bounds__(256) void k_geom(
    const float* __restrict__ pos, const int* __restrict__ snd, const int* __restrict__ rcv,
    float* __restrict__ Yb, float* __restrict__ Bb, float* __restrict__ Eb)
{
  int e = blockIdx.x*256 + threadIdx.x;
  if (e >= EE) return;
  int s = snd[e], r = rcv[e];
  float dx = pos[3*r  ]-pos[3*s  ];
  float dy = pos[3*r+1]-pos[3*s+1];
  float dz = pos[3*r+2]-pos[3*s+2];
  float d  = sqrtf(dx*dx+dy*dy+dz*dz);
  float dsafe = fmaxf(d, 1e-9f);
  float inv = 1.0f/dsafe;
  float x = dx*inv, y = dy*inv, z = dz*inv;
  const float c1=1.7320508075688772f, c2=3.872983346207417f, c3=1.118033988749895f;
  float Y[SH];
  Y[0]=1.0f; Y[1]=c1*x; Y[2]=c1*y; Y[3]=c1*z;
  Y[4]=c2*x*y; Y[5]=c2*y*z; Y[6]=c3*(3.0f*z*z-1.0f); Y[7]=c2*x*z; Y[8]=0.5f*c2*(x*x-y*y);
  #pragma unroll
  for (int i=0;i<SH;i++) Yb[(size_t)e*SH+i]=Y[i];
  float sc = sqrtf(2.0f/RMAX)*inv;
  // sin(k*th) by recurrence: s_k = 2cos(th) s_{k-1} - s_{k-2}
  float th = 3.14159265358979f*dsafe/RMAX;
  float s1 = sinf(th), cth = cosf(th);
  float skm = 0.0f, sk = s1, twoc = 2.0f*cth;
  #pragma unroll
  for (int k=0;k<NB;k++){
    Bb[(size_t)e*NB+k] = sc*sk;
    float sn = twoc*sk - skm;
    skm = sk; sk = sn;
  }
  float tt = fminf(d/RMAX, 1.0f-1e-6f);
  float envv = (d < RMAX) ? expf(-tt*tt/(1.0f-tt*tt)) : 0.0f;
  Eb[e]=envv;
}

// ---------------- x init from embedding table ----------------
__global__ __launch_bounds__(256) void k_init(
    const int* __restrict__ spec, const float* __restrict__ et, float* __restrict__ x)
{
  int i = blockIdx.x*256 + threadIdx.x;
  int n = i >> 6, f = i & 63;
  x[i] = et[spec[n]*FF + f];
}

// ---------------- CSR build ----------------
__global__ __launch_bounds__(256) void k_deg(const int* __restrict__ rcv, int* __restrict__ deg)
{
  int e = blockIdx.x*256 + threadIdx.x;
  if (e < EE) atomicAdd(&deg[rcv[e]], 1);
}

__global__ __launch_bounds__(256) void k_scan(const int* __restrict__ deg,
                                              int* __restrict__ off, int* __restrict__ cur)
{
  __shared__ int part[256];
  int t = threadIdx.x;
  int base = t*32;
  int s = 0;
  for (int i=0;i<32;i++) s += deg[base+i];
  part[t] = s;
  __syncthreads();
  for (int o2=1;o2<256;o2<<=1){
    int v = (t>=o2)? part[t-o2] : 0;
    __syncthreads();
    part[t] += v;
    __syncthreads();
  }
  int run = part[t]-s;
  for (int i=0;i<32;i++){
    off[base+i]=run; cur[base+i]=run;
    run += deg[base+i];
  }
  if (t==255) off[NN]=run;
}

__global__ __launch_bounds__(256) void k_fill(const int* __restrict__ rcv,
                                              int* __restrict__ cur, int* __restrict__ eidx)
{
  int e = blockIdx.x*256 + threadIdx.x;
  if (e < EE){
    int p = atomicAdd(&cur[rcv[e]], 1);
    eidx[p] = e;
  }
}

// ---------------- H = softplus(B @ W1) in bf16, one layer ----------------
__global__ __launch_bounds__(256) void k_h(
    const float* __restrict__ Bb, const float* __restrict__ W1l,
    unsigned short* __restrict__ H)
{
  int i = blockIdx.x*256 + threadIdx.x;   // over EE*FF
  int e = i >> 6, f = i & 63;
  const float* Brow = Bb + (size_t)e*NB;
  float h = 0.0f;
  #pragma unroll
  for (int k=0;k<NB;k++) h += Brow[k]*W1l[k*FF + f];
  H[i] = f2bf(softplus_f(h));
}

// ---------------- pack W2 (both layers) into MFMA B-frag layout, permuted cols ----------------
__global__ __launch_bounds__(256) void k_w2pack(
    const float* __restrict__ W2, unsigned short* __restrict__ Bp)
{
  int id = blockIdx.x*256 + threadIdx.x;      // 24576 total
  int j  = id & 7;
  int l  = (id>>3) & 63;
  int s  = (id>>9) & 1;
  int rem = id >> 10;                         // li*12 + t
  int t  = rem % 12;
  int li = rem / 12;
  int k  = s*32 + (l>>4)*8 + j;
  int colp = t*16 + (l&15);
  int f = colp & 63, c = colp >> 6;
  float v = W2[(size_t)li*FF*192 + k*192 + 3*f + c];
  Bp[id] = f2bf(v);
}

// ---------------- pack W_read (both layers) into B-frag layout ----------------
// Wrp[((li*18+ks)*8+t)*512 + l*8 + j] = W_read[li][ks*32 + (l>>4)*8 + j][t*16 + (l&15)]
__global__ __launch_bounds__(256) void k_wrpack(
    const float* __restrict__ Wr, unsigned short* __restrict__ Wrp)
{
  int id = blockIdx.x*256 + threadIdx.x;      // 147456 total
  int j  = id & 7;
  int l  = (id>>3) & 63;
  int t  = (id>>9) & 7;
  int rem = id >> 12;                         // li*18 + ks
  int ks = rem % 18;
  int li = rem / 18;
  int k  = ks*32 + (l>>4)*8 + j;
  int col = t*16 + (l&15);
  float v = Wr[(size_t)li*576*DDIM + k*DDIM + col];
  Wrp[id] = f2bf(v);
}

// ---------------- O = H @ W2  (bf16 MFMA), O stored bf16 with permuted cols ----------------
__global__ __launch_bounds__(256) void k_gemm2(
    const unsigned short* __restrict__ H, const unsigned short* __restrict__ Bpl,
    unsigned short* __restrict__ O)
{
  int tid = threadIdx.x;
  int lane = tid & 63, wv = tid >> 6;
  int r0 = (blockIdx.x*4 + wv) * 16;
  int mrow = lane & 15, kgrp = lane >> 4;
  const short8v* Arow = (const short8v*)(H + ((size_t)(r0 + mrow))*FF + kgrp*8);
  short8v a0 = Arow[0];
  short8v a1 = Arow[4];
  #pragma unroll
  for (int t=0;t<12;t++){
    short8v b0 = *(const short8v*)(Bpl + ((size_t)(t*2+0)*64 + lane)*8);
    short8v b1 = *(const short8v*)(Bpl + ((size_t)(t*2+1)*64 + lane)*8);
    float4v acc = {0.0f,0.0f,0.0f,0.0f};
    acc = __builtin_amdgcn_mfma_f32_16x16x32_bf16(a0, b0, acc, 0, 0, 0);
    acc = __builtin_amdgcn_mfma_f32_16x16x32_bf16(a1, b1, acc, 0, 0, 0);
    #pragma unroll
    for (int i=0;i<4;i++){
      int row = r0 + kgrp*4 + i;
      O[(size_t)row*192 + t*16 + mrow] = f2bf(acc[i]);
    }
  }
}

// ---------------- gather: per-node wave; writes bf16 agg + f32 c0 ----------------
__global__ __launch_bounds__(256) void k_gather(
  const float* __restrict__ Yb, const float* __restrict__ Eb,
  const int* __restrict__ snd, const int* __restrict__ off, const int* __restrict__ eidx,
  const float* __restrict__ x, const unsigned short* __restrict__ O,
  unsigned short* __restrict__ aggb, float* __restrict__ c0)
{
  int lane = threadIdx.x & 63, wv = threadIdx.x >> 6;
  int n = blockIdx.x*4 + wv;
  int js = off[n], je = off[n+1];
  float acc[SH];
  #pragma unroll
  for (int i=0;i<SH;i++) acc[i]=0.0f;
  for (int j=js;j<je;j++){
    int e = eidx[j];
    const unsigned short* orow = O + (size_t)e*192;
    float o0 = bf2f(orow[lane]);
    float o1 = bf2f(orow[64+lane]);
    float o2 = bf2f(orow[128+lane]);
    float scale = Eb[e]*INV_AVG*x[snd[e]*FF+lane];
    const float* y = Yb + (size_t)e*SH;
    float p0=o0*scale, p1=o1*scale, p2=o2*scale;
    acc[0]+=y[0]*p0;
    acc[1]+=y[1]*p1; acc[2]+=y[2]*p1; acc[3]+=y[3]*p1;
    acc[4]+=y[4]*p2; acc[5]+=y[5]*p2; acc[6]+=y[6]*p2;
    acc[7]+=y[7]*p2; acc[8]+=y[8]*p2;
  }
  unsigned short* db = aggb + (size_t)n*576 + lane*SH;
  #pragma unroll
  for (int i=0;i<SH;i++) db[i]=f2bf(acc[i]);
  c0[(size_t)n*FF + lane] = acc[0];
}

// ---------------- readout via MFMA: emb[:, colOff:+128] = aggb @ Wrp ----------------
__global__ __launch_bounds__(256) void k_read_mfma(
    const unsigned short* __restrict__ aggb, const unsigned short* __restrict__ Wrpl,
    float* __restrict__ emb, int colOff)
{
  int tid = threadIdx.x;
  int lane = tid & 63, wv = tid >> 6;
  int r0 = (blockIdx.x*4 + wv)*16;
  int mrow = lane & 15, kgrp = lane >> 4;
  float4v acc[8];
  #pragma unroll
  for (int t=0;t<8;t++){ acc[t][0]=0.f; acc[t][1]=0.f; acc[t][2]=0.f; acc[t][3]=0.f; }
  const unsigned short* arow = aggb + (size_t)(r0+mrow)*576 + kgrp*8;
  #pragma unroll 3
  for (int ks=0; ks<18; ++ks){
    short8v a = *(const short8v*)(arow + ks*32);
    #pragma unroll
    for (int t=0;t<8;t++){
      short8v b = *(const short8v*)(Wrpl + (((size_t)ks*8+t)*64 + lane)*8);
      acc[t] = __builtin_amdgcn_mfma_f32_16x16x32_bf16(a, b, acc[t], 0, 0, 0);
    }
  }
  #pragma unroll
  for (int t=0;t<8;t++){
    #pragma unroll
    for (int i=0;i<4;i++){
      emb[(size_t)(r0 + kgrp*4 + i)*256 + colOff + t*16 + mrow] = acc[t][i];
    }
  }
}

// ---------------- node update: x = silu(c0@W_upd + x@W_self) ----------------
__global__ __launch_bounds__(256) void k_upd(
    const float* __restrict__ c0, const float* __restrict__ xin,
    const float* __restrict__ Wu, const float* __restrict__ Wsf, float* __restrict__ xout)
{
  __shared__ float sWu[FF*FF], sWs[FF*FF];
  __shared__ float sA[4][FF], sX[4][FF];
  int t = threadIdx.x;
  for (int i=t;i<FF*FF;i+=256){ sWu[i]=Wu[i]; sWs[i]=Wsf[i]; }
  int lane = t&63, wv = t>>6;
  int n = blockIdx.x*4 + wv;
  sA[wv][lane] = c0[(size_t)n*FF + lane];
  sX[wv][lane] = xin[n*FF + lane];
  __syncthreads();
  float a=0.0f;
  #pragma unroll 8
  for (int k=0;k<FF;k++) a += sA[wv][k]*sWu[k*FF+lane] + sX[wv][k]*sWs[k*FF+lane];
  float sg = 1.0f/(1.0f+expf(-a));
  xout[n*FF+lane] = a*sg;
}

// ---------------- focus logits ----------------
__global__ __launch_bounds__(256) void k_focus(
    const float* __restrict__ emb, const float* __restrict__ wf, float* __restrict__ out)
{
  int lane = threadIdx.x&63, wv = threadIdx.x>>6;
  int n = blockIdx.x*4 + wv;
  float a=0.0f;
  #pragma unroll
  for (int j=0;j<4;j++) a += emb[(size_t)n*256 + j*64 + lane]*wf[j*64+lane];
  #pragma unroll
  for (int off=32; off>0; off>>=1) a += __shfl_down(a, off, 64);
  if (lane==0) out[n]=a;
}

// ---------------- species head + sprod prep (one block per graph) ----------------
__global__ __launch_bounds__(256) void k_spec(
    const float* __restrict__ emb, const int* __restrict__ nnode, const int* __restrict__ tspec,
    const float* __restrict__ Ws1, const float* __restrict__ Ws2,
    const float* __restrict__ stab,
    float* __restrict__ outSp, float* __restrict__ sprodB)
{
  __shared__ float sf[256], sh2[128];
  int g = blockIdx.x, t = threadIdx.x;
  int fi = 0;
  for (int i=0;i<g;i++) fi += nnode[i];
  int ts = tspec[g];
  float fv = emb[(size_t)fi*256 + t];
  sf[t] = fv;
  sprodB[g*256 + t] = fv*stab[ts*256+t];
  __syncthreads();
  if (t < 128){
    float a=0.0f;
    #pragma unroll 4
    for (int k=0;k<256;k++) a += sf[k]*Ws1[k*128+t];
    sh2[t] = softplus_f(a);
  }
  __syncthreads();
  if (t < 5){
    float a=0.0f;
    for (int k=0;k<128;k++) a += sh2[k]*Ws2[k*5+t];
    outSp[g*5+t]=a;
  }
}

// ---------------- pos head: grid (8 slices, 32 graphs), 128 threads ----------------
__global__ __launch_bounds__(128) void k_pos(
    const float* __restrict__ sprodB, const float* __restrict__ Wpos,
    float* __restrict__ outPos)
{
  __shared__ float ssp[256];
  int g = blockIdx.y, t = threadIdx.x;
  int p = blockIdx.x*128 + t;
  ssp[t]     = sprodB[g*256 + t];
  ssp[t+128] = sprodB[g*256 + 128 + t];
  __syncthreads();
  float a=0.0f;
  #pragma unroll 4
  for (int k=0;k<256;k++) a += ssp[k]*Wpos[(size_t)k*1024 + p];
  outPos[(size_t)g*1024 + p] = a;
}

extern "C" void kernel_launch(void* const* d_in, const int* in_sizes, int n_in,
                              void* d_out, int out_size, void* d_ws, size_t ws_size,
                              hipStream_t stream)
{
  const float* positions = (const float*)d_in[0];
  const int*   species   = (const int*)  d_in[1];
  const int*   senders   = (const int*)  d_in[2];
  const int*   receivers = (const int*)  d_in[3];
  const int*   n_node    = (const int*)  d_in[4];
  const int*   tspec     = (const int*)  d_in[5];
  const float* emb_table = (const float*)d_in[6];
  const float* W1        = (const float*)d_in[7];
  const float* W2        = (const float*)d_in[8];
  const float* W_self    = (const float*)d_in[9];
  const float* W_upd     = (const float*)d_in[10];
  const float* W_read    = (const float*)d_in[11];
  const float* w_focus   = (const float*)d_in[12];
  const float* Ws1       = (const float*)d_in[13];
  const float* Ws2       = (const float*)d_in[14];
  const float* stab      = (const float*)d_in[15];
  const float* W_pos     = (const float*)d_in[16];

  char* base = (char*)d_ws;
  size_t ofs = 0;
  auto alloc = [&](size_t bytes)->char*{
    char* p = base + ofs;
    ofs = (ofs + bytes + 255) & ~(size_t)255;
    return p;
  };
  float* Yb   = (float*)alloc((size_t)EE*SH*4);
  float* Bb   = (float*)alloc((size_t)EE*NB*4);
  float* Eb   = (float*)alloc((size_t)EE*4);
  float* xA   = (float*)alloc((size_t)NN*FF*4);
  float* xB   = (float*)alloc((size_t)NN*FF*4);
  float* c0   = (float*)alloc((size_t)NN*FF*4);
  float* emb  = (float*)alloc((size_t)NN*256*4);
  float* sprodB=(float*)alloc((size_t)GG*256*4);
  int*   deg  = (int*)  alloc((size_t)NN*4);
  int*   off  = (int*)  alloc((size_t)(NN+1)*4);
  int*   cur  = (int*)  alloc((size_t)NN*4);
  int*   eidx = (int*)  alloc((size_t)EE*4);
  unsigned short* H    = (unsigned short*)alloc((size_t)EE*FF*2);
  unsigned short* O    = (unsigned short*)alloc((size_t)EE*192*2);
  unsigned short* aggb = (unsigned short*)alloc((size_t)NN*576*2);
  unsigned short* Bp   = (unsigned short*)alloc((size_t)2*12*2*64*8*2);
  unsigned short* Wrp  = (unsigned short*)alloc((size_t)2*18*8*64*8*2);

  float* outFocus = (float*)d_out;
  float* outSp    = outFocus + NN;
  float* outPos   = outSp + GG*5;

  // geometry + embeddings + CSR + weight packs
  k_geom<<<EE/256,256,0,stream>>>(positions,senders,receivers,Yb,Bb,Eb);
  k_init<<<NN*FF/256,256,0,stream>>>(species,emb_table,xA);
  hipMemsetAsync(deg, 0, NN*sizeof(int), stream);
  k_deg<<<EE/256,256,0,stream>>>(receivers,deg);
  k_scan<<<1,256,0,stream>>>(deg,off,cur);
  k_fill<<<EE/256,256,0,stream>>>(receivers,cur,eidx);
  k_w2pack<<<96,256,0,stream>>>(W2,Bp);
  k_wrpack<<<576,256,0,stream>>>(W_read,Wrp);

  // ---- layer 0 ----
  k_h<<<EE*FF/256,256,0,stream>>>(Bb,W1,H);
  k_gemm2<<<EE/64,256,0,stream>>>(H,Bp,O);
  k_gather<<<NN/4,256,0,stream>>>(Yb,Eb,senders,off,eidx,xA,O,aggb,c0);
  k_read_mfma<<<NN/64,256,0,stream>>>(aggb,Wrp,emb,0);
  k_upd<<<NN/4,256,0,stream>>>(c0,xA,W_upd,W_self,xB);

  // ---- layer 1 ----
  k_h<<<EE*FF/256,256,0,stream>>>(Bb,W1+NB*FF,H);
  k_gemm2<<<EE/64,256,0,stream>>>(H,Bp+(size_t)12*2*64*8,O);
  k_gather<<<NN/4,256,0,stream>>>(Yb,Eb,senders,off,eidx,xB,O,aggb,c0);
  k_read_mfma<<<NN/64,256,0,stream>>>(aggb,Wrp+(size_t)18*8*64*8,emb,DDIM);

  // ---- heads ----
  k_focus<<<NN/4,256,0,stream>>>(emb,w_focus,outFocus);
  k_spec<<<GG,256,0,stream>>>(emb,n_node,tspec,Ws1,Ws2,stab,outSp,sprodB);
  k_pos<<<dim3(8,GG),128,0,stream>>>(sprodB,W_pos,outPos);
}